// Round 6
// baseline (159.150 us; speedup 1.0000x reference)
//
#include <hip/hip_runtime.h>

// Decoder: N=4096 LSTM seqs (K=16 x B=256), H=64, T=50, GMM head (GC=16, PD=2).
// Round 6: barrier-free recurrence.
//  prep (grid 267): blocks 0-255: GEMM zx->{gc(256), h0, c0} per 16 samples;
//                   blocks 256+: pack Whh + proj weights into MFMA B-frag hi/lo.
//  lstm (grid 256x256): 4 waves/block, each wave OWNS 4 samples end-to-end.
//      Sample s lives in A-row 4s -> gates land in-lane (lane g=sample, c=unit%16)
//      -> cell update fully in-lane, h via wave-private LDS, NO barriers at all.
//  head (grid 1024): proj via MFMA + in-lane GMM + atomicAdd (R5 k2).

#define T_ 50
typedef __attribute__((ext_vector_type(8))) short short8;
typedef __attribute__((ext_vector_type(4))) float f32x4;
#define MFMA(a,b,c) __builtin_amdgcn_mfma_f32_16x16x32_bf16(a,b,c,0,0,0)

// ws layout (bytes):
#define HOUT_B 0u            // ushort Hout[50][4096][64]  = 26,214,400
#define GCT_B  26214400u     // float gcT[256][4096]       = 4,194,304
#define H0_B   30408704u     // u32  h0u32[4096][64]       = 1,048,576
#define C0_B   31457280u     // float c0f[4096][64]        = 1,048,576
#define WF_B   32505856u     // short8 WF[4096 + 1536]
#define PRJ_SLOT 4096

__device__ __forceinline__ float sigf(float x)  { return 1.0f / (1.0f + __expf(-x)); }
__device__ __forceinline__ float tanh_(float x) { return 1.0f - 2.0f / (__expf(2.0f * x) + 1.0f); }

__device__ __forceinline__ void splitf(float f, unsigned short& hi, unsigned short& lo) {
    unsigned b = __float_as_uint(f);
    hi = (unsigned short)(b >> 16);
    float fh = __uint_as_float(b & 0xffff0000u);
    lo = (unsigned short)(__float_as_uint(f - fh) >> 16);
}

__device__ __forceinline__ void pack8(const float* p, short8& hi, short8& lo) {
    #pragma unroll
    for (int e = 0; e < 8; ++e) {
        unsigned short h, l;
        splitf(p[e], h, l);
        hi[e] = (short)h; lo[e] = (short)l;
    }
}

union U8 { short8 s; unsigned u[4]; };

// ---------------- prep: GEMM (gc,h0,c0) + weight pack ----------------
__launch_bounds__(256, 1)
__global__ void prep_kernel(
    const float* __restrict__ x,   const float* __restrict__ z,
    const float* __restrict__ Wh0, const float* __restrict__ bh0,
    const float* __restrict__ Wc0, const float* __restrict__ bc0,
    const float* __restrict__ Wih, const float* __restrict__ Whh,
    const float* __restrict__ bih, const float* __restrict__ bhh,
    const float* __restrict__ Wpi, const float* __restrict__ Wmu,
    const float* __restrict__ Wls, const float* __restrict__ Wcorr,
    float* __restrict__ gcT, unsigned* __restrict__ h0u32,
    float* __restrict__ c0f, short8* __restrict__ WF)
{
    const int j = threadIdx.x;
    if (blockIdx.x >= 256) {
        // ---- pack part
        int tid = (blockIdx.x - 256)*256 + j;
        if (tid < 2048) {              // Whh frags
            int lane = tid & 63, r = tid >> 6;        // r = tile*2 + ks, tile = tau*4+ublk
            int ks = r & 1, tile = r >> 1;
            int tau = tile >> 2, ublk = tile & 3;
            int g = lane >> 4, c = lane & 15;
            const float* src = Whh + (tau*64 + 16*ublk + c)*64 + ks*32 + g*8;
            short8 hi, lo; pack8(src, hi, lo);
            WF[(r*2 + 0)*64 + lane] = hi;
            WF[(r*2 + 1)*64 + lane] = lo;
        } else if (tid < 2816) {       // proj frags
            int t2 = tid - 2048;
            int lane = t2 & 63, r = t2 >> 6;          // r = pt*2 + ks
            int ks = r & 1, pt = r >> 1;
            int g = lane >> 4, c = lane & 15;
            int r3 = pt*16 + c;
            const float* p;
            if      (r3 < 16) p = Wpi   + r3*64;
            else if (r3 < 48) p = Wmu   + (r3-16)*64;
            else if (r3 < 80) p = Wls   + (r3-48)*64;
            else              p = Wcorr + (r3-80)*64;
            short8 hi, lo; pack8(p + ks*32 + g*8, hi, lo);
            WF[PRJ_SLOT + (r*2 + 0)*64 + lane] = hi;
            WF[PRJ_SLOT + (r*2 + 1)*64 + lane] = lo;
        }
        return;
    }

    // ---- GEMM part: 16 samples, 24 col-tiles (16 gc + 4 h0 + 4 c0)
    __shared__ __align__(16) float ZXL[16*324];
    const int blk = blockIdx.x;
    for (int e = j; e < 16*320; e += 256) {
        int s = e / 320, k = e - s*320;
        int n = blk*16 + s, b = n & 255;
        ZXL[s*324 + k] = (k < 64) ? z[n*64 + k] : x[b*256 + (k - 64)];
    }
    __syncthreads();

    const int w = j >> 6, l = j & 63, g = l >> 4, c = l & 15;
    f32x4 acc[6];
    const float* src[6];
    #pragma unroll
    for (int i = 0; i < 6; ++i) {
        int T = w*6 + i;
        float bias;
        if (T < 16)      { int ga = T*16 + c;      bias = bih[ga] + bhh[ga]; src[i] = Wih + ga*322; }
        else if (T < 20) { int u  = (T-16)*16 + c; bias = bh0[u];            src[i] = Wh0 + u*320; }
        else             { int u  = (T-20)*16 + c; bias = bc0[u];            src[i] = Wc0 + u*320; }
        acc[i] = (f32x4){bias, bias, bias, bias};
    }
    for (int ks = 0; ks < 10; ++ks) {
        short8 ah, al;
        pack8(&ZXL[c*324 + ks*32 + g*8], ah, al);
        #pragma unroll
        for (int i = 0; i < 6; ++i) {
            short8 bh, bl;
            pack8(src[i] + ks*32 + g*8, bh, bl);
            acc[i] = MFMA(ah, bh, acc[i]);
            acc[i] = MFMA(ah, bl, acc[i]);
            acc[i] = MFMA(al, bh, acc[i]);
        }
    }
    #pragma unroll
    for (int i = 0; i < 6; ++i) {
        int T = w*6 + i;
        if (T < 16) {
            *reinterpret_cast<f32x4*>(gcT + (T*16 + c)*4096 + blk*16 + 4*g) = acc[i];
        } else if (T < 20) {
            int u = (T-16)*16 + c;
            #pragma unroll
            for (int r = 0; r < 4; ++r) {
                unsigned short hh, ll; splitf(acc[i][r], hh, ll);
                h0u32[(blk*16 + 4*g + r)*64 + u] = ((unsigned)hh << 16) | ll;
            }
        } else {
            int u = (T-20)*16 + c;
            #pragma unroll
            for (int r = 0; r < 4; ++r)
                c0f[(blk*16 + 4*g + r)*64 + u] = acc[i][r];
        }
    }
}

// ---------------- lstm: barrier-free recurrence ----------------
__launch_bounds__(256, 1)
__global__ void lstm_kernel(
    const float* __restrict__ inp_seqs, const float* __restrict__ pred_seqs,
    const float* __restrict__ Wih,
    const float* __restrict__ gcT, const unsigned* __restrict__ h0u32,
    const float* __restrict__ c0f, unsigned short* __restrict__ Hout,
    const short8* __restrict__ WF)
{
    __shared__ unsigned HLs[4][16*65];
    __shared__ float    DQs[4][51*8];
    const int j = threadIdx.x;
    const int wv = j >> 6, l = j & 63, g = l >> 4, c = l & 15;
    unsigned* HL = HLs[wv];
    float* DQ = DQs[wv];
    const int nb = blockIdx.x*16 + wv*4;      // this wave's samples nb..nb+3

    // zero HL (wave-local; junk A-rows must be 0 forever)
    for (int e = l; e < 16*65; e += 64) HL[e] = 0u;
    // d-inputs: DQ[t*8 + s*2 + comp], t=0 -> present, t>=1 -> FUT[t-1]
    for (int e = l; e < 51*8; e += 64) {
        int t = e >> 3, rem = e & 7, s = rem >> 1, comp = rem & 1;
        int b = (nb + s) & 255;
        DQ[e] = (t == 0) ? inp_seqs[b*192 + 188 + comp]
                         : pred_seqs[b*1200 + (t-1)*24 + 20 + comp];
    }

    // Whh B-frags (register-resident)
    short8 WB[4][4][2][2];
    #pragma unroll
    for (int tau = 0; tau < 4; ++tau)
        #pragma unroll
        for (int ub = 0; ub < 4; ++ub)
            #pragma unroll
            for (int ks = 0; ks < 2; ++ks)
                #pragma unroll
                for (int p = 0; p < 2; ++p)
                    WB[tau][ub][ks][p] = WF[(((tau*4 + ub)*2 + ks)*2 + p)*64 + l];

    // gc scalars (this lane: sample nb+g, gate col T*16+c)
    float gcs[16];
    #pragma unroll
    for (int T = 0; T < 16; ++T) gcs[T] = gcT[(T*16 + c)*4096 + nb + g];

    // d-weights (Wih cols 320,321), per (tau, ublk) for unit 16*ublk+c
    float wd0[4][4], wd1[4][4];
    #pragma unroll
    for (int tau = 0; tau < 4; ++tau)
        #pragma unroll
        for (int ub = 0; ub < 4; ++ub) {
            int ga = tau*64 + 16*ub + c;
            wd0[tau][ub] = Wih[ga*322 + 320];
            wd1[tau][ub] = Wih[ga*322 + 321];
        }

    // c0 + h0 (h0 into HL row 4g, hi|lo packed)
    float cst[4];
    #pragma unroll
    for (int ub = 0; ub < 4; ++ub) {
        cst[ub] = c0f[(nb + g)*64 + 16*ub + c];
        HL[(4*g)*65 + 16*ub + c] = h0u32[(nb + g)*64 + 16*ub + c];
    }
    asm volatile("s_waitcnt lgkmcnt(0)" ::: "memory");

    const f32x4 zero4 = (f32x4){0.0f, 0.0f, 0.0f, 0.0f};

    for (int t = 0; t < T_; ++t) {
        // A-frags of h_t: lane (g,c) = A-row c, k = 8g+e (+32 for kslice 1)
        unsigned hv[16];
        #pragma unroll
        for (int e = 0; e < 8; ++e) hv[e]     = HL[c*65 + 8*g + e];
        #pragma unroll
        for (int e = 0; e < 8; ++e) hv[8 + e] = HL[c*65 + 32 + 8*g + e];
        U8 A0h, A0l, A1h, A1l;
        #pragma unroll
        for (int q = 0; q < 4; ++q) {
            A0h.u[q] = (hv[2*q] >> 16)      | (hv[2*q+1] & 0xffff0000u);
            A0l.u[q] = (hv[2*q] & 0xffffu)  | (hv[2*q+1] << 16);
            A1h.u[q] = (hv[8+2*q] >> 16)     | (hv[8+2*q+1] & 0xffff0000u);
            A1l.u[q] = (hv[8+2*q] & 0xffffu) | (hv[8+2*q+1] << 16);
        }

        float2 dv = *reinterpret_cast<const float2*>(&DQ[t*8 + g*2]);

        float gv[4][4];
        #pragma unroll
        for (int tau = 0; tau < 4; ++tau) {
            #pragma unroll
            for (int ub = 0; ub < 4; ++ub) {
                f32x4 a = MFMA(A0h.s, WB[tau][ub][0][0], zero4);
                a = MFMA(A0l.s, WB[tau][ub][0][0], a);
                a = MFMA(A0h.s, WB[tau][ub][0][1], a);
                a = MFMA(A1h.s, WB[tau][ub][1][0], a);
                a = MFMA(A1l.s, WB[tau][ub][1][0], a);
                a = MFMA(A1h.s, WB[tau][ub][1][1], a);
                gv[tau][ub] = a[0] + gcs[tau*4 + ub];
            }
        }

        // cell: this lane owns (sample nb+g, units {16*ub+c})
        #pragma unroll
        for (int ub = 0; ub < 4; ++ub) {
            float iv = gv[0][ub] + dv.x*wd0[0][ub] + dv.y*wd1[0][ub];
            float fv = gv[1][ub] + dv.x*wd0[1][ub] + dv.y*wd1[1][ub];
            float gg = gv[2][ub] + dv.x*wd0[2][ub] + dv.y*wd1[2][ub];
            float ov = gv[3][ub] + dv.x*wd0[3][ub] + dv.y*wd1[3][ub];
            float cc = sigf(fv)*cst[ub] + sigf(iv)*tanh_(gg);
            cst[ub] = cc;
            float hn = sigf(ov)*tanh_(cc);
            unsigned short hh, ll; splitf(hn, hh, ll);
            HL[(4*g)*65 + 16*ub + c] = ((unsigned)hh << 16) | ll;
            Hout[(size_t)(t*4096 + nb + g)*64 + 16*ub + c] = hh;
        }
        asm volatile("s_waitcnt lgkmcnt(0)" ::: "memory");
    }
}

// ---------------- head: proj + GMM ----------------
__launch_bounds__(256, 3)
__global__ void head_kernel(const float* __restrict__ pred_seqs,
                            const float* __restrict__ bpi, const float* __restrict__ bmu,
                            const float* __restrict__ bls, const float* __restrict__ bcorr,
                            const unsigned short* __restrict__ Hin,
                            const short8* __restrict__ WF,
                            float* __restrict__ out)
{
    __shared__ __align__(16) float PL[4][1600];   // per-wave 16 x 100
    const int j = threadIdx.x;
    const int w = j >> 6;
    const int l = j & 63;
    const int g = l >> 4;
    const int c = l & 15;
    const int blk = blockIdx.x;
    const int set = blk >> 2, chunk = blk & 3;
    const int t0 = (chunk*25) >> 1, t1 = ((chunk+1)*25) >> 1;

    float bias[6];
    #pragma unroll
    for (int pt = 0; pt < 6; ++pt) {
        int r3 = pt*16 + c;
        bias[pt] = (r3 < 16) ? bpi[r3] : (r3 < 48) ? bmu[r3-16]
                 : (r3 < 80) ? bls[r3-48] : bcorr[r3-80];
    }

    const int s = l >> 2, q4 = l & 3;
    const int n_s = set*16 + s, b_s = n_s & 255;
    float* PLw = &PL[w][0];
    float sum_local = 0.0f;

    for (int t = t0 + w; t < t1; t += 4) {
        const unsigned short* hp = Hin + (size_t)(t*4096 + set*16 + c)*64;
        short8 ah0 = *reinterpret_cast<const short8*>(hp + g*8);
        short8 ah1 = *reinterpret_cast<const short8*>(hp + 32 + g*8);
        #pragma unroll
        for (int pt = 0; pt < 6; ++pt) {
            short8 B00 = WF[PRJ_SLOT + ((pt*2 + 0)*2 + 0)*64 + l];
            short8 B01 = WF[PRJ_SLOT + ((pt*2 + 0)*2 + 1)*64 + l];
            short8 B10 = WF[PRJ_SLOT + ((pt*2 + 1)*2 + 0)*64 + l];
            short8 B11 = WF[PRJ_SLOT + ((pt*2 + 1)*2 + 1)*64 + l];
            f32x4 p = (f32x4){bias[pt], bias[pt], bias[pt], bias[pt]};
            p = MFMA(ah0, B00, p);
            p = MFMA(ah0, B01, p);
            p = MFMA(ah1, B10, p);
            p = MFMA(ah1, B11, p);
            #pragma unroll
            for (int r = 0; r < 4; ++r) PLw[(4*g + r)*100 + pt*16 + c] = p[r];
        }
        asm volatile("s_waitcnt lgkmcnt(0)" ::: "memory");
        __builtin_amdgcn_sched_barrier(0);

        float2 tv = *reinterpret_cast<const float2*>(pred_seqs + b_s*1200 + t*24 + 20);
        float a[4], m = -1e30f, Ppi = 0.0f;
        #pragma unroll
        for (int i = 0; i < 4; ++i) {
            int cq = q4*4 + i;
            float pi = PLw[s*100 + cq];
            float2 mu = *reinterpret_cast<const float2*>(PLw + s*100 + 16 + 2*cq);
            float2 ls = *reinterpret_cast<const float2*>(PLw + s*100 + 48 + 2*cq);
            float co = PLw[s*100 + 80 + cq];
            float l0 = fminf(fmaxf(ls.x, -10.0f), 10.0f);
            float l1 = fminf(fmaxf(ls.y, -10.0f), 10.0f);
            float z0 = (tv.x - mu.x) * __expf(-l0);
            float z1 = (tv.y - mu.y) * __expf(-l1);
            float ct = tanh_(co);
            float omr = 1.0f - ct*ct;
            float quad = z0*z0 + z1*z1 - 2.0f*ct*z0*z1;
            float comp = -1.8378770664093453f - (l0 + l1) - 0.5f*__logf(omr) - 0.5f*quad/omr;
            a[i] = pi + comp;
            m = fmaxf(m, a[i]);
            Ppi += __expf(pi);
        }
        m = fmaxf(m, __shfl_xor(m, 1));
        m = fmaxf(m, __shfl_xor(m, 2));
        float E = __expf(a[0]-m) + __expf(a[1]-m) + __expf(a[2]-m) + __expf(a[3]-m);
        E   += __shfl_xor(E, 1);   E   += __shfl_xor(E, 2);
        Ppi += __shfl_xor(Ppi, 1); Ppi += __shfl_xor(Ppi, 2);
        float logp = m + __logf(E) - __logf(Ppi);
        sum_local += fminf(logp, 50.0f);
    }
    if (q4 == 0) atomicAdd(out + n_s, sum_local);
}

extern "C" void kernel_launch(void* const* d_in, const int* in_sizes, int n_in,
                              void* d_out, int out_size, void* d_ws, size_t ws_size,
                              hipStream_t stream) {
    const float* x     = (const float*)d_in[0];
    const float* z     = (const float*)d_in[1];
    const float* iseq  = (const float*)d_in[2];
    const float* pseq  = (const float*)d_in[3];
    const float* Wh0   = (const float*)d_in[4];
    const float* bh0   = (const float*)d_in[5];
    const float* Wc0   = (const float*)d_in[6];
    const float* bc0   = (const float*)d_in[7];
    const float* Wih   = (const float*)d_in[8];
    const float* Whh   = (const float*)d_in[9];
    const float* bih   = (const float*)d_in[10];
    const float* bhh   = (const float*)d_in[11];
    const float* Wpi   = (const float*)d_in[12];
    const float* bpi   = (const float*)d_in[13];
    const float* Wmu   = (const float*)d_in[14];
    const float* bmu   = (const float*)d_in[15];
    const float* Wls   = (const float*)d_in[16];
    const float* bls   = (const float*)d_in[17];
    const float* Wcorr = (const float*)d_in[18];
    const float* bcorr = (const float*)d_in[19];
    float* out = (float*)d_out;

    char* ws = (char*)d_ws;
    unsigned short* Hout = (unsigned short*)(ws + HOUT_B);
    float*    gcT   = (float*)(ws + GCT_B);
    unsigned* h0u32 = (unsigned*)(ws + H0_B);
    float*    c0f   = (float*)(ws + C0_B);
    short8*   WF    = (short8*)(ws + WF_B);

    prep_kernel<<<267, 256, 0, stream>>>(x, z, Wh0, bh0, Wc0, bc0, Wih, Whh,
                                         bih, bhh, Wpi, Wmu, Wls, Wcorr,
                                         gcT, h0u32, c0f, WF);
    hipMemsetAsync(d_out, 0, 4096 * sizeof(float), stream);
    lstm_kernel<<<256, 256, 0, stream>>>(iseq, pseq, Wih, gcT, h0u32, c0f,
                                         Hout, (const short8*)WF);
    head_kernel<<<1024, 256, 0, stream>>>(pseq, bpi, bmu, bls, bcorr,
                                          (const unsigned short*)Hout,
                                          (const short8*)WF, out);
}

// Round 7
// 98.502 us; speedup vs baseline: 1.6157x; 1.6157x over previous
//
#include <hip/hip_runtime.h>

// Decoder: N=4096 LSTM seqs (K=16 x B=256), H=64, T=50, GMM head (GC=16, PD=2).
// Round 7: single fused kernel, 256 blocks x 768 threads (12 waves) x 16 samples.
//  - waves 0-3  (LSTM): wave w owns i/f/g/o tiles for units [16w,16w+16);
//    24 MFMA/step (3-pass hi/lo), cell fully in registers, h -> LDS bf16 hi/lo.
//  - waves 4-7  (proj): 6 proj tiles (2/2/1/1) on H_t -> PL double buffer.
//  - waves 8-11 (GMM): 1 component/lane (16 samples x 16 comps = 256 lanes),
//    logsumexp via 16-lane shfl, runs on PL written the previous step.
//  Each SIMD hosts exactly {LSTM, proj, GMM} waves -> stall hiding across roles.
//  ONE barrier per step. Prologue GEMM (16 gc tiles + h0 + c0) spread over all
//  12 waves, 2 tiles each, routed via LDS. No global h traffic. LDS 30 KB.

#define T_ 50
typedef __attribute__((ext_vector_type(8))) short short8;
typedef __attribute__((ext_vector_type(4))) float f32x4;
#define MFMA(a,b,c) __builtin_amdgcn_mfma_f32_16x16x32_bf16(a,b,c,0,0,0)

__device__ __forceinline__ float sigf(float x)  { return 1.0f / (1.0f + __expf(-x)); }
__device__ __forceinline__ float tanh_(float x) { return 1.0f - 2.0f / (__expf(2.0f * x) + 1.0f); }

__device__ __forceinline__ void splitf(float f, unsigned short& hi, unsigned short& lo) {
    unsigned b = __float_as_uint(f);
    hi = (unsigned short)(b >> 16);
    float fh = __uint_as_float(b & 0xffff0000u);
    lo = (unsigned short)(__float_as_uint(f - fh) >> 16);
}

__device__ __forceinline__ void pack8(const float* p, short8& hi, short8& lo) {
    #pragma unroll
    for (int e = 0; e < 8; ++e) {
        unsigned short h, l;
        splitf(p[e], h, l);
        hi[e] = (short)h; lo[e] = (short)l;
    }
}

__launch_bounds__(768, 3)
__global__ void decoder_kernel(
    const float* __restrict__ x,       const float* __restrict__ z,
    const float* __restrict__ inp_seqs,const float* __restrict__ pred_seqs,
    const float* __restrict__ Wh0,     const float* __restrict__ bh0,
    const float* __restrict__ Wc0,     const float* __restrict__ bc0,
    const float* __restrict__ Wih,     const float* __restrict__ Whh,
    const float* __restrict__ bih,     const float* __restrict__ bhh,
    const float* __restrict__ Wpi,     const float* __restrict__ bpi,
    const float* __restrict__ Wmu,     const float* __restrict__ bmu,
    const float* __restrict__ Wls,     const float* __restrict__ bls,
    const float* __restrict__ Wcorr,   const float* __restrict__ bcorr,
    float* __restrict__ out)
{
    // floats: region A [0,5184): ZXL(16x324) -> {gcX[0,4096), c0X[4096,5120)}
    //         -> loop: {PL0[0,1600), PL1[1600,3200), FUT[3200,4800), PRS[4800,4832)}
    //         HF [5184,7488): 4 ushort arrays 16x72 (h0 hi, h0 lo, h1 hi, h1 lo)
    __shared__ __align__(16) float smem[7488];
    float* ZXL = smem;
    float* gcX = smem;
    float* c0X = smem + 4096;
    float* PL0 = smem;
    float* PL1 = smem + 1600;
    float* FUT = smem + 3200;
    float* PRS = smem + 4800;
    unsigned short* HF0h = (unsigned short*)(smem + 5184);
    unsigned short* HF0l = HF0h + 1152;
    unsigned short* HF1h = HF0h + 2304;
    unsigned short* HF1l = HF0h + 3456;

    const int j = threadIdx.x;
    const int w = j >> 6;       // wave 0..11
    const int l = j & 63;
    const int g = l >> 4;       // k-group / D-row-group
    const int c = l & 15;       // A-row / B-col
    const int blk = blockIdx.x;

    // ---- stage ZXL (16 samples x 320)
    for (int e = j; e < 16*320; e += 768) {
        int s = e / 320, k = e - s*320;
        int n = blk*16 + s, b = n & 255;
        ZXL[s*324 + k] = (k < 64) ? z[n*64 + k] : x[b*256 + (k - 64)];
    }
    __syncthreads();

    // ---- prologue: 2 GEMM tiles per wave.
    // round A: gc tile tA = w (tiles 0..11); round B: w<4 -> gc tile 12+w;
    // 4<=w<8 -> h0 units 16(w-4)+c; w>=8 -> c0 units 16(w-8)+c.
    const int tA = w;
    f32x4 accA, accB;
    const float* srcA;
    const float* srcB;
    int tB = -1;
    {
        int qA_ = tA >> 2, ubA_ = tA & 3;
        int gaA = qA_*64 + 16*ubA_ + c;
        float bA = bih[gaA] + bhh[gaA];
        accA = (f32x4){bA, bA, bA, bA};
        srcA = Wih + gaA*322;
        float bB;
        if (w < 4) {
            tB = 12 + w;
            int qB_ = tB >> 2, ubB_ = tB & 3;
            int gaB = qB_*64 + 16*ubB_ + c;
            bB = bih[gaB] + bhh[gaB];
            srcB = Wih + gaB*322;
        } else if (w < 8) {
            int u = 16*(w-4) + c;
            bB = bh0[u];
            srcB = Wh0 + u*320;
        } else {
            int u = 16*(w-8) + c;
            bB = bc0[u];
            srcB = Wc0 + u*320;
        }
        accB = (f32x4){bB, bB, bB, bB};
    }
    for (int ks = 0; ks < 10; ++ks) {
        short8 ah, al;
        pack8(&ZXL[c*324 + ks*32 + g*8], ah, al);
        short8 b1h, b1l; pack8(srcA + ks*32 + g*8, b1h, b1l);
        accA = MFMA(ah, b1h, accA); accA = MFMA(ah, b1l, accA); accA = MFMA(al, b1h, accA);
        short8 b2h, b2l; pack8(srcB + ks*32 + g*8, b2h, b2l);
        accB = MFMA(ah, b2h, accB); accB = MFMA(ah, b2l, accB); accB = MFMA(al, b2h, accB);
    }
    __syncthreads();   // ZXL fully consumed

    // ---- scatter prologue results (gcX/c0X overlay ZXL region; HF0 separate)
    #pragma unroll
    for (int r = 0; r < 4; ++r) gcX[tA*256 + (4*g + r)*16 + c] = accA[r];
    if (w < 4) {
        #pragma unroll
        for (int r = 0; r < 4; ++r) gcX[tB*256 + (4*g + r)*16 + c] = accB[r];
    } else if (w < 8) {
        #pragma unroll
        for (int r = 0; r < 4; ++r) {
            unsigned short hh, ll; splitf(accB[r], hh, ll);
            HF0h[(4*g + r)*72 + 16*(w-4) + c] = hh;
            HF0l[(4*g + r)*72 + 16*(w-4) + c] = ll;
        }
    } else {
        #pragma unroll
        for (int r = 0; r < 4; ++r) c0X[(4*g + r)*64 + 16*(w-8) + c] = accB[r];
    }
    __syncthreads();

    // ---- role pickup
    f32x4 gc[4];
    float cst[4];
    short8 WH[4][2], WL[4][2];
    float wd0[4], wd1[4];
    short8 qAh0, qAl0, qAh1, qAl1, qBh0, qBl0, qBh1, qBl1;
    float pbA = 0.0f, pbB = 0.0f;
    int ptA = 0, nproj = 0;
    const int s3 = 4*(w - 8) + g;    // GMM sample (valid for w>=8)
    const int g3 = c;                // GMM component
    float sum = 0.0f;

    if (w < 4) {
        #pragma unroll
        for (int q = 0; q < 4; ++q) {
            #pragma unroll
            for (int r = 0; r < 4; ++r)
                gc[q][r] = gcX[(q*4 + w)*256 + (4*g + r)*16 + c];
            int ga = q*64 + 16*w + c;
            pack8(Whh + ga*64 +      g*8, WH[q][0], WL[q][0]);
            pack8(Whh + ga*64 + 32 + g*8, WH[q][1], WL[q][1]);
            wd0[q] = Wih[ga*322 + 320];
            wd1[q] = Wih[ga*322 + 321];
        }
        #pragma unroll
        for (int r = 0; r < 4; ++r) cst[r] = c0X[(4*g + r)*64 + 16*w + c];
    } else if (w < 8) {
        int v = w - 4;
        nproj = (v < 2) ? 2 : 1;
        ptA = (v < 2) ? 2*v : 4 + (v - 2);
        auto projrow = [&](int r3, const float*& p, float& b) {
            if      (r3 < 16) { p = Wpi   + r3*64;      b = bpi[r3]; }
            else if (r3 < 48) { p = Wmu   + (r3-16)*64; b = bmu[r3-16]; }
            else if (r3 < 80) { p = Wls   + (r3-48)*64; b = bls[r3-48]; }
            else              { p = Wcorr + (r3-80)*64; b = bcorr[r3-80]; }
        };
        const float* p;
        projrow(ptA*16 + c, p, pbA);
        pack8(p +      g*8, qAh0, qAl0);
        pack8(p + 32 + g*8, qAh1, qAl1);
        if (nproj == 2) {
            projrow((ptA+1)*16 + c, p, pbB);
            pack8(p +      g*8, qBh0, qBl0);
            pack8(p + 32 + g*8, qBh1, qBl1);
        }
    }
    __syncthreads();   // gcX/c0X reads done

    // ---- stage FUT/PRS (overwrites gcX/c0X region)
    for (int e = j; e < T_*32; e += 768) {
        int t = e >> 5, rem = e & 31, s = rem >> 1;
        int b = (blk*16 + s) & 255;
        FUT[e] = pred_seqs[b*1200 + t*24 + 20 + (rem & 1)];
    }
    if (j < 32) {
        int b = (blk*16 + (j >> 1)) & 255;
        PRS[j] = inp_seqs[b*192 + 188 + (j & 1)];
    }
    __syncthreads();

    auto do_proj = [&](const unsigned short* Hh, const unsigned short* Hl, float* PLw) {
        short8 ah0 = *reinterpret_cast<const short8*>(Hh + c*72 +      g*8);
        short8 al0 = *reinterpret_cast<const short8*>(Hl + c*72 +      g*8);
        short8 ah1 = *reinterpret_cast<const short8*>(Hh + c*72 + 32 + g*8);
        short8 al1 = *reinterpret_cast<const short8*>(Hl + c*72 + 32 + g*8);
        f32x4 pA = (f32x4){pbA, pbA, pbA, pbA};
        pA = MFMA(ah0, qAh0, pA); pA = MFMA(ah0, qAl0, pA); pA = MFMA(al0, qAh0, pA);
        pA = MFMA(ah1, qAh1, pA); pA = MFMA(ah1, qAl1, pA); pA = MFMA(al1, qAh1, pA);
        #pragma unroll
        for (int r = 0; r < 4; ++r) PLw[(4*g + r)*100 + ptA*16 + c] = pA[r];
        if (nproj == 2) {
            f32x4 pB = (f32x4){pbB, pbB, pbB, pbB};
            pB = MFMA(ah0, qBh0, pB); pB = MFMA(ah0, qBl0, pB); pB = MFMA(al0, qBh0, pB);
            pB = MFMA(ah1, qBh1, pB); pB = MFMA(ah1, qBl1, pB); pB = MFMA(al1, qBh1, pB);
            #pragma unroll
            for (int r = 0; r < 4; ++r) PLw[(4*g + r)*100 + (ptA+1)*16 + c] = pB[r];
        }
    };
    auto do_gmm = [&](const float* pl, const float* fut2) {
        const float* pls = pl + s3*100;
        float a_pi = pls[g3];
        float a_m0 = pls[16 + 2*g3], a_m1 = pls[17 + 2*g3];
        float l0   = pls[48 + 2*g3], l1   = pls[49 + 2*g3];
        float a_co = pls[80 + g3];
        float v0 = fut2[s3*2], v1 = fut2[s3*2 + 1];
        l0 = fminf(fmaxf(l0, -10.0f), 10.0f);
        l1 = fminf(fmaxf(l1, -10.0f), 10.0f);
        float z0 = (v0 - a_m0) * __expf(-l0);
        float z1 = (v1 - a_m1) * __expf(-l1);
        float ct = tanh_(a_co);
        float omr = 1.0f - ct*ct;
        float quad = z0*z0 + z1*z1 - 2.0f*ct*z0*z1;
        float comp = -1.8378770664093453f - (l0 + l1) - 0.5f*__logf(omr) - 0.5f*quad/omr;
        float a = a_pi + comp;
        float m1v = a, m2v = a_pi;
        #pragma unroll
        for (int off = 1; off < 16; off <<= 1) {
            m1v = fmaxf(m1v, __shfl_xor(m1v, off));
            m2v = fmaxf(m2v, __shfl_xor(m2v, off));
        }
        float e1 = __expf(a - m1v), e2 = __expf(a_pi - m2v);
        #pragma unroll
        for (int off = 1; off < 16; off <<= 1) {
            e1 += __shfl_xor(e1, off);
            e2 += __shfl_xor(e2, off);
        }
        float logp = (m1v + __logf(e1)) - (m2v + __logf(e2));
        sum += fminf(logp, 50.0f);
    };

    // ---- main loop: ONE barrier per step
    for (int t = 0; t < T_; ++t) {
        const unsigned short* Hh = (t & 1) ? HF1h : HF0h;
        const unsigned short* Hl = (t & 1) ? HF1l : HF0l;
        if (w < 4) {
            unsigned short* Nh = (t & 1) ? HF0h : HF1h;
            unsigned short* Nl = (t & 1) ? HF0l : HF1l;
            short8 ah0 = *reinterpret_cast<const short8*>(Hh + c*72 +      g*8);
            short8 al0 = *reinterpret_cast<const short8*>(Hl + c*72 +      g*8);
            short8 ah1 = *reinterpret_cast<const short8*>(Hh + c*72 + 32 + g*8);
            short8 al1 = *reinterpret_cast<const short8*>(Hl + c*72 + 32 + g*8);
            const float* dptr = (t == 0) ? PRS : (FUT + (t-1)*32);
            float2 dv[4];
            #pragma unroll
            for (int r = 0; r < 4; ++r)
                dv[r] = *reinterpret_cast<const float2*>(dptr + (4*g + r)*2);
            f32x4 aq[4];
            #pragma unroll
            for (int q = 0; q < 4; ++q) {
                #pragma unroll
                for (int r = 0; r < 4; ++r)
                    aq[q][r] = gc[q][r] + dv[r].x*wd0[q] + dv[r].y*wd1[q];
                aq[q] = MFMA(ah0, WH[q][0], aq[q]);
                aq[q] = MFMA(ah0, WL[q][0], aq[q]);
                aq[q] = MFMA(al0, WH[q][0], aq[q]);
                aq[q] = MFMA(ah1, WH[q][1], aq[q]);
                aq[q] = MFMA(ah1, WL[q][1], aq[q]);
                aq[q] = MFMA(al1, WH[q][1], aq[q]);
            }
            #pragma unroll
            for (int r = 0; r < 4; ++r) {
                float cc = sigf(aq[1][r])*cst[r] + sigf(aq[0][r])*tanh_(aq[2][r]);
                cst[r] = cc;
                float hv = sigf(aq[3][r])*tanh_(cc);
                unsigned short hh, ll; splitf(hv, hh, ll);
                Nh[(4*g + r)*72 + 16*w + c] = hh;
                Nl[(4*g + r)*72 + 16*w + c] = ll;
            }
        } else if (w < 8) {
            if (t >= 1) do_proj(Hh, Hl, (t & 1) ? PL1 : PL0);
        } else {
            if (t >= 2) do_gmm((t & 1) ? PL0 : PL1, FUT + (t-2)*32);
        }
        __syncthreads();
    }

    // ---- epilogue: proj(H_50) (parity HF0) -> PL0; GMM(H_49) from PL1;
    //      barrier; GMM(H_50) from PL0; write out.
    if (w >= 4 && w < 8) do_proj(HF0h, HF0l, PL0);
    if (w >= 8) do_gmm(PL1, FUT + 48*32);
    __syncthreads();
    if (w >= 8) {
        do_gmm(PL0, FUT + 49*32);
        if (g3 == 0) out[blk*16 + s3] = sum;
    }
}

extern "C" void kernel_launch(void* const* d_in, const int* in_sizes, int n_in,
                              void* d_out, int out_size, void* d_ws, size_t ws_size,
                              hipStream_t stream) {
    const float* x     = (const float*)d_in[0];
    const float* z     = (const float*)d_in[1];
    const float* iseq  = (const float*)d_in[2];
    const float* pseq  = (const float*)d_in[3];
    const float* Wh0   = (const float*)d_in[4];
    const float* bh0   = (const float*)d_in[5];
    const float* Wc0   = (const float*)d_in[6];
    const float* bc0   = (const float*)d_in[7];
    const float* Wih   = (const float*)d_in[8];
    const float* Whh   = (const float*)d_in[9];
    const float* bih   = (const float*)d_in[10];
    const float* bhh   = (const float*)d_in[11];
    const float* Wpi   = (const float*)d_in[12];
    const float* bpi   = (const float*)d_in[13];
    const float* Wmu   = (const float*)d_in[14];
    const float* bmu   = (const float*)d_in[15];
    const float* Wls   = (const float*)d_in[16];
    const float* bls   = (const float*)d_in[17];
    const float* Wcorr = (const float*)d_in[18];
    const float* bcorr = (const float*)d_in[19];
    float* out = (float*)d_out;

    decoder_kernel<<<256, 768, 0, stream>>>(x, z, iseq, pseq, Wh0, bh0, Wc0, bc0,
                                            Wih, Whh, bih, bhh, Wpi, bpi, Wmu, bmu,
                                            Wls, bls, Wcorr, bcorr, out);
}